// Round 1
// baseline (77226.514 us; speedup 1.0000x reference)
//
#include <hip/hip_runtime.h>
#include <hip/hip_cooperative_groups.h>

namespace cg = cooperative_groups;

#define NTHREADS 512
#define BT 16   // batch tile per workgroup

constexpr int Bsz = 256, Tst = 128, HID = 1440;
constexpr int ORN = 384, PN = 112, LN = 64, KC = 864, MB = 16, OBS = 64;

struct Params {
  const float *obs, *h, *in_orn_w, *in_orn_b, *W_oto, *W_lto, *W_otp, *W_ltp, *W_ptp,
              *W_otl, *W_ptl, *W_ltl, *W_ktk, *W_mtk, *W_ptk, *W_ktm,
              *b_orn, *b_pn, *b_ln, *b_kc, *b_mbon, *readout_w, *readout_b;
  float *orn0, *orn1, *pn0, *pn1, *ln0, *ln1, *kc0, *kc1, *mbon, *y, *h2;
};

template <int K>
__device__ __forceinline__ float dot4(const float* __restrict__ w, const float* __restrict__ a) {
  float acc = 0.f;
  const float4* w4 = (const float4*)w;
  const float4* a4 = (const float4*)a;
#pragma unroll 4
  for (int i = 0; i < K / 4; ++i) {
    float4 wv = w4[i], av = a4[i];
    acc += wv.x * av.x; acc += wv.y * av.y; acc += wv.z * av.z; acc += wv.w * av.w;
  }
  return acc;
}

// stage a [BT x width] slab of a global state array (row-major [B][width]) into
// LDS at row stride `stride` (floats), segment offset `off`.
__device__ __forceinline__ void load_seg(float* dst, int stride, int off,
                                         const float* g, int width, int b0, int tid) {
  int w4 = width >> 2;
  const float4* g4 = (const float4*)(g + (size_t)b0 * width);
  for (int idx = tid; idx < BT * w4; idx += NTHREADS) {
    int b = idx / w4, k = idx - b * w4;
    *(float4*)(dst + b * stride + off + 4 * k) = g4[(size_t)b * w4 + k];
  }
}

__global__ void __launch_bounds__(NTHREADS, 1)
conn_kernel(Params P) {
  cg::grid_group grid = cg::this_grid();
  // max act stride = 868 (KC stage). 16*868*4B = 55.5 KB. strides 452/564/868 are
  // ==4 or ==20 (mod 32): 16-lane batch access is 2-way bank-aliased -> free.
  __shared__ float act[BT * 868];
  __shared__ float xs[BT * 24];
  const int tid = threadIdx.x;
  const int wg = blockIdx.x, bg = wg >> 4, ng = wg & 15, b0 = bg * BT;

  // ---- init: scatter h into parity-1 state buffers (step 0 reads parity 1) ----
  if (ng == 0) {
    for (int idx = tid; idx < BT * HID; idx += NTHREADS) {
      int b = idx / HID, pos = idx - b * HID, gb = b0 + b;
      float v = P.h[(size_t)gb * HID + pos];
      if      (pos < 384)  P.orn1[(size_t)gb * ORN + pos] = v;
      else if (pos < 496)  P.pn1[gb * PN + (pos - 384)] = v;
      else if (pos < 560)  P.ln1[gb * LN + (pos - 496)] = v;
      else if (pos < 1424) P.kc1[(size_t)gb * KC + (pos - 560)] = v;
      else                 P.mbon[gb * MB + (pos - 1424)] = v;
    }
  }
  grid.sync();

  for (int s = 0; s < Tst * 4; ++s) {
    const int t = s >> 2, i = s & 3, p = s & 1;
    float* ornN = p ? P.orn1 : P.orn0;  const float* ornO = p ? P.orn0 : P.orn1;
    float* pnN  = p ? P.pn1  : P.pn0;   const float* pnO  = p ? P.pn0  : P.pn1;
    float* lnN  = p ? P.ln1  : P.ln0;   const float* lnO  = p ? P.ln0  : P.ln1;
    float* kcN  = p ? P.kc1  : P.kc0;   const float* kcO  = p ? P.kc0  : P.kc1;

    // ================= Stage A: orn_i (+ mbon_{i-1}) =================
    if (i == 0) {  // x_t slice for our 24 orn neurons, once per timestep
      for (int o = tid; o < BT * 24; o += NTHREADS) {
        int b = o / 24, jl = o - b * 24, j = ng * 24 + jl;
        xs[b * 24 + jl] = P.in_orn_b[j]
          + dot4<OBS>(P.in_orn_w + (size_t)j * OBS,
                      P.obs + ((size_t)(b0 + b) * Tst + t) * OBS);
      }
    }
    load_seg(act, 452, 0,   ornO, ORN, b0, tid);
    load_seg(act, 452, 384, lnO,  LN,  b0, tid);
    __syncthreads();
    if (tid < 24 * BT) {
      int b = tid & 15, jl = tid >> 4, j = ng * 24 + jl;
      float acc = xs[b * 24 + jl] + P.b_orn[j]
        + dot4<ORN>(P.W_oto + (size_t)j * ORN, act + b * 452)
        + dot4<LN> (P.W_lto + (size_t)j * LN,  act + b * 452 + 384);
      ornN[(size_t)(b0 + b) * ORN + j] = tanhf(acc);
    }
    __syncthreads();
    if (s > 0) {  // mbon_{s-1} = tanh(kc_{s-1} @ W_ktm^T + b); split-K over 8 lanes
      load_seg(act, 868, 0, kcO, KC, b0, tid);
      __syncthreads();
      if (tid < 128) {
        int b = tid >> 3, ks = tid & 7;
        float part = dot4<108>(P.W_ktm + (size_t)ng * KC + ks * 108,
                               act + b * 868 + ks * 108);
        part += __shfl_xor(part, 1);
        part += __shfl_xor(part, 2);
        part += __shfl_xor(part, 4);
        if (ks == 0)
          P.mbon[(b0 + b) * MB + ng] = tanhf(part + P.b_mbon[ng]);
      }
    }
    grid.sync();

    // ================= Stage B: pn_i (+ y_{t-1} on first inner step) =================
    load_seg(act, 564, 0,   ornN, ORN, b0, tid);
    load_seg(act, 564, 384, lnO,  LN,  b0, tid);
    load_seg(act, 564, 448, pnO,  PN,  b0, tid);
    __syncthreads();
    if (tid < 7 * BT) {
      int b = tid & 15, jl = tid >> 4, j = ng * 7 + jl;
      float acc = P.b_pn[j]
        + dot4<ORN>(P.W_otp + (size_t)j * ORN, act + b * 564)
        + dot4<LN> (P.W_ltp + (size_t)j * LN,  act + b * 564 + 384)
        + dot4<PN> (P.W_ptp + (size_t)j * PN,  act + b * 564 + 448);
      pnN[(size_t)(b0 + b) * PN + j] = tanhf(acc);
    }
    if (i == 0 && s > 0) {  // y_{t-1}: rank-16 readout from mbon (global, synced)
      for (int o = tid; o < 90 * BT; o += NTHREADS) {
        int b = o / 90, jl = o - b * 90, j = ng * 90 + jl;
        float acc = P.readout_b[j]
          + dot4<MB>(P.readout_w + (size_t)j * MB, P.mbon + (size_t)(b0 + b) * MB);
        P.y[((size_t)(b0 + b) * Tst + (t - 1)) * HID + j] = acc;
      }
    }
    grid.sync();

    // ================= Stage C: ln_i and kc_i =================
    load_seg(act, 564, 0,   ornN, ORN, b0, tid);
    load_seg(act, 564, 384, pnN,  PN,  b0, tid);
    load_seg(act, 564, 496, lnO,  LN,  b0, tid);
    __syncthreads();
    if (tid < 4 * BT) {
      int b = tid & 15, jl = tid >> 4, j = ng * 4 + jl;
      float acc = P.b_ln[j]
        + dot4<ORN>(P.W_otl + (size_t)j * ORN, act + b * 564)
        + dot4<PN> (P.W_ptl + (size_t)j * PN,  act + b * 564 + 384)
        + dot4<LN> (P.W_ltl + (size_t)j * LN,  act + b * 564 + 496);
      lnN[(size_t)(b0 + b) * LN + j] = tanhf(acc);
    }
    __syncthreads();
    load_seg(act, 868, 0, kcO, KC, b0, tid);
    __syncthreads();
    for (int o = tid; o < 54 * BT; o += NTHREADS) {
      int b = o & 15, jl = o >> 4, j = ng * 54 + jl;
      float acc = P.b_kc[j]
        + dot4<KC>(P.W_ktk + (size_t)j * KC, act + b * 868)
        + dot4<MB>(P.W_mtk + (size_t)j * MB, P.mbon + (size_t)(b0 + b) * MB)
        + dot4<PN>(P.W_ptk + (size_t)j * PN, pnN + (size_t)(b0 + b) * PN);
      kcN[(size_t)(b0 + b) * KC + j] = tanhf(acc);
    }
    grid.sync();
  }

  // ================= tail: mbon_{511}, y_{127}, h2 =================
  load_seg(act, 868, 0, P.kc1, KC, b0, tid);  // s=511 wrote parity-1
  __syncthreads();
  if (tid < 128) {
    int b = tid >> 3, ks = tid & 7;
    float part = dot4<108>(P.W_ktm + (size_t)ng * KC + ks * 108,
                           act + b * 868 + ks * 108);
    part += __shfl_xor(part, 1);
    part += __shfl_xor(part, 2);
    part += __shfl_xor(part, 4);
    if (ks == 0)
      P.mbon[(b0 + b) * MB + ng] = tanhf(part + P.b_mbon[ng]);
  }
  grid.sync();
  for (int o = tid; o < 90 * BT; o += NTHREADS) {
    int b = o / 90, jl = o - b * 90, j = ng * 90 + jl;
    float acc = P.readout_b[j]
      + dot4<MB>(P.readout_w + (size_t)j * MB, P.mbon + (size_t)(b0 + b) * MB);
    P.y[((size_t)(b0 + b) * Tst + (Tst - 1)) * HID + j] = acc;
  }
  for (int idx = tid; idx < BT * 90; idx += NTHREADS) {
    int b = idx / 90, pos = idx - b * 90, gb = b0 + b;
    float v; int hp;
    if      (pos < 24) { v = P.orn1[(size_t)gb * ORN + ng * 24 + pos]; hp = ng * 24 + pos; }
    else if (pos < 31) { int l = pos - 24; v = P.pn1[gb * PN + ng * 7 + l]; hp = 384 + ng * 7 + l; }
    else if (pos < 35) { int l = pos - 31; v = P.ln1[gb * LN + ng * 4 + l]; hp = 496 + ng * 4 + l; }
    else if (pos < 89) { int l = pos - 35; v = P.kc1[(size_t)gb * KC + ng * 54 + l]; hp = 560 + ng * 54 + l; }
    else               { v = P.mbon[gb * MB + ng]; hp = 1424 + ng; }
    P.h2[(size_t)gb * HID + hp] = v;
  }
}

extern "C" void kernel_launch(void* const* d_in, const int* in_sizes, int n_in,
                              void* d_out, int out_size, void* d_ws, size_t ws_size,
                              hipStream_t stream) {
  Params P;
  P.obs       = (const float*)d_in[0];
  P.h         = (const float*)d_in[1];
  P.in_orn_w  = (const float*)d_in[2];
  P.in_orn_b  = (const float*)d_in[3];
  P.W_oto     = (const float*)d_in[4];
  P.W_lto     = (const float*)d_in[5];
  P.W_otp     = (const float*)d_in[6];
  P.W_ltp     = (const float*)d_in[7];
  P.W_ptp     = (const float*)d_in[8];
  P.W_otl     = (const float*)d_in[9];
  P.W_ptl     = (const float*)d_in[10];
  P.W_ltl     = (const float*)d_in[11];
  P.W_ktk     = (const float*)d_in[12];
  P.W_mtk     = (const float*)d_in[13];
  P.W_ptk     = (const float*)d_in[14];
  P.W_ktm     = (const float*)d_in[15];
  P.b_orn     = (const float*)d_in[16];
  P.b_pn      = (const float*)d_in[17];
  P.b_ln      = (const float*)d_in[18];
  P.b_kc      = (const float*)d_in[19];
  P.b_mbon    = (const float*)d_in[20];
  P.readout_w = (const float*)d_in[21];
  P.readout_b = (const float*)d_in[22];

  float* ws = (float*)d_ws;
  size_t off = 0;
  P.orn0 = ws + off; off += (size_t)Bsz * ORN;
  P.orn1 = ws + off; off += (size_t)Bsz * ORN;
  P.pn0  = ws + off; off += (size_t)Bsz * PN;
  P.pn1  = ws + off; off += (size_t)Bsz * PN;
  P.ln0  = ws + off; off += (size_t)Bsz * LN;
  P.ln1  = ws + off; off += (size_t)Bsz * LN;
  P.kc0  = ws + off; off += (size_t)Bsz * KC;
  P.kc1  = ws + off; off += (size_t)Bsz * KC;
  P.mbon = ws + off; off += (size_t)Bsz * MB;

  P.y  = (float*)d_out;
  P.h2 = (float*)d_out + (size_t)Bsz * Tst * HID;

  void* args[] = { &P };
  hipLaunchCooperativeKernel((void*)conn_kernel, dim3(256), dim3(NTHREADS), args, 0, stream);
}

// Round 2
// 66825.769 us; speedup vs baseline: 1.1556x; 1.1556x over previous
//
#include <hip/hip_runtime.h>
#include <hip/hip_cooperative_groups.h>

namespace cg = cooperative_groups;

#define NTHREADS 512
#define BT 16   // batch tile per workgroup

constexpr int Bsz = 256, Tst = 128, HID = 1440;
constexpr int ORN = 384, PN = 112, LN = 64, KC = 864, MB = 16, OBS = 64;

struct Params {
  const float *obs, *h, *in_orn_w, *in_orn_b, *W_oto, *W_lto, *W_otp, *W_ltp, *W_ptp,
              *W_otl, *W_ptl, *W_ltl, *W_ktk, *W_mtk, *W_ptk, *W_ktm,
              *b_orn, *b_pn, *b_ln, *b_kc, *b_mbon, *readout_w, *readout_b;
  float *orn0, *orn1, *pn0, *pn1, *ln0, *ln1, *kc0, *kc1, *mbon, *y, *h2;
  int *bar;
};

// ---- ILP-4 dot: 4 independent accumulators (serial-chain FMA was latency-bound) ----
template <int K>
__device__ __forceinline__ float dot4(const float* __restrict__ w, const float* __restrict__ a) {
  const float4* w4 = (const float4*)w;
  const float4* a4 = (const float4*)a;
  float x0 = 0.f, x1 = 0.f, x2 = 0.f, x3 = 0.f;
#pragma unroll 4
  for (int i = 0; i < K / 4; ++i) {
    float4 wv = w4[i], av = a4[i];
    x0 = fmaf(wv.x, av.x, x0); x1 = fmaf(wv.y, av.y, x1);
    x2 = fmaf(wv.z, av.z, x2); x3 = fmaf(wv.w, av.w, x3);
  }
  return (x0 + x1) + (x2 + x3);
}

// ---- dual-output dot: one act stream feeds two weight rows (halves LDS traffic) ----
template <int K>
__device__ __forceinline__ void ddot(const float* __restrict__ w0, const float* __restrict__ w1,
                                     const float* __restrict__ a, float& r0, float& r1) {
  const float4* W0 = (const float4*)w0;
  const float4* W1 = (const float4*)w1;
  const float4* A  = (const float4*)a;
  float x0=0,x1=0,x2=0,x3=0, y0=0,y1=0,y2=0,y3=0;
#pragma unroll 4
  for (int i = 0; i < K / 4; ++i) {
    float4 av = A[i], u = W0[i], v = W1[i];
    x0 = fmaf(u.x, av.x, x0); x1 = fmaf(u.y, av.y, x1);
    x2 = fmaf(u.z, av.z, x2); x3 = fmaf(u.w, av.w, x3);
    y0 = fmaf(v.x, av.x, y0); y1 = fmaf(v.y, av.y, y1);
    y2 = fmaf(v.z, av.z, y2); y3 = fmaf(v.w, av.w, y3);
  }
  r0 += (x0 + x1) + (x2 + x3);
  r1 += (y0 + y1) + (y2 + y3);
}

__device__ __forceinline__ void load_seg(float* dst, int stride, int off,
                                         const float* g, int width, int b0, int tid) {
  int w4 = width >> 2;
  const float4* g4 = (const float4*)(g + (size_t)b0 * width);
  for (int idx = tid; idx < BT * w4; idx += NTHREADS) {
    int b = idx / w4, k = idx - b * w4;
    *(float4*)(dst + b * stride + off + 4 * k) = g4[(size_t)b * w4 + k];
  }
}

// ---- 16-WG sense-free barrier (per batch group), device-scope atomics ----
__device__ __forceinline__ void bar_sync(int* cnt, int* gen, int& lg, int tid) {
  __syncthreads();
  if (tid == 0) {
    __threadfence();            // writeback our L2 (release)
    int target = ++lg;
    int old = __hip_atomic_fetch_add(cnt, 1, __ATOMIC_ACQ_REL, __HIP_MEMORY_SCOPE_AGENT);
    if (old == 15) {
      __hip_atomic_store(cnt, 0, __ATOMIC_RELAXED, __HIP_MEMORY_SCOPE_AGENT);
      __hip_atomic_fetch_add(gen, 1, __ATOMIC_RELEASE, __HIP_MEMORY_SCOPE_AGENT);
    } else {
      while (__hip_atomic_load(gen, __ATOMIC_ACQUIRE, __HIP_MEMORY_SCOPE_AGENT) < target)
        __builtin_amdgcn_s_sleep(1);
    }
    __threadfence();            // invalidate caches (acquire)
  }
  __syncthreads();
}

__global__ void __launch_bounds__(NTHREADS, 1)
conn_kernel(Params P) {
  cg::grid_group grid = cg::this_grid();
  // strides 452/564/996 are all ==4 (mod 32): 16-lane batch access is 2-way bank-aliased -> free.
  // 16*996*4 + 16*24*4 = 65280 B <= 64 KiB static LDS limit.
  __shared__ float act[BT * 996];
  __shared__ float xs[BT * 24];
  const int tid = threadIdx.x;
  const int wg = blockIdx.x, bg = wg >> 4, ng = wg & 15, b0 = bg * BT;
  int* cnt = P.bar + bg * 64;
  int* gen = P.bar + bg * 64 + 16;
  int lg = 0;

  // ---- init: scatter h into parity-1 state buffers; init this bg's barrier ----
  if (ng == 0) {
    if (tid == 0) { *cnt = 0; *gen = 0; }
    for (int idx = tid; idx < BT * HID; idx += NTHREADS) {
      int b = idx / HID, pos = idx - b * HID, gb = b0 + b;
      float v = P.h[(size_t)gb * HID + pos];
      if      (pos < 384)  P.orn1[(size_t)gb * ORN + pos] = v;
      else if (pos < 496)  P.pn1[gb * PN + (pos - 384)] = v;
      else if (pos < 560)  P.ln1[gb * LN + (pos - 496)] = v;
      else if (pos < 1424) P.kc1[(size_t)gb * KC + (pos - 560)] = v;
      else                 P.mbon[gb * MB + (pos - 1424)] = v;
    }
  }
  grid.sync();  // once: publishes init + barrier zeros

  for (int s = 0; s < Tst * 4; ++s) {
    const int t = s >> 2, i = s & 3, p = s & 1;
    float* ornN = p ? P.orn1 : P.orn0;  const float* ornO = p ? P.orn0 : P.orn1;
    float* pnN  = p ? P.pn1  : P.pn0;   const float* pnO  = p ? P.pn0  : P.pn1;
    float* lnN  = p ? P.ln1  : P.ln0;   const float* lnO  = p ? P.ln0  : P.ln1;
    float* kcN  = p ? P.kc1  : P.kc0;   const float* kcO  = p ? P.kc0  : P.kc1;

    // ================= Stage A: orn_i (threads 0-191) + mbon_{s-1} (192-319) =================
    load_seg(act, 452, 0,   ornO, ORN, b0, tid);
    load_seg(act, 452, 384, lnO,  LN,  b0, tid);
    if (i == 0 && tid >= 320) {  // x_t slice, once per timestep, overlaps staging
      for (int o = tid - 320; o < BT * 24; o += 192) {
        int b = o / 24, jl = o - b * 24, j = ng * 24 + jl;
        xs[b * 24 + jl] = P.in_orn_b[j]
          + dot4<OBS>(P.in_orn_w + (size_t)j * OBS,
                      P.obs + ((size_t)(b0 + b) * Tst + t) * OBS);
      }
    }
    __syncthreads();
    if (tid < 192) {
      int b = tid & 15, jp = tid >> 4;
      int j0 = ng * 24 + jp * 2, j1 = j0 + 1;
      float r0 = xs[b * 24 + jp * 2]     + P.b_orn[j0];
      float r1 = xs[b * 24 + jp * 2 + 1] + P.b_orn[j1];
      ddot<ORN>(P.W_oto + (size_t)j0 * ORN, P.W_oto + (size_t)j1 * ORN, act + b * 452, r0, r1);
      ddot<LN> (P.W_lto + (size_t)j0 * LN,  P.W_lto + (size_t)j1 * LN,  act + b * 452 + 384, r0, r1);
      ornN[(size_t)(b0 + b) * ORN + j0] = tanhf(r0);
      ornN[(size_t)(b0 + b) * ORN + j1] = tanhf(r1);
    } else if (tid < 320 && s > 0) {  // mbon: direct L2 reads (no reuse -> no LDS staging)
      int idx = tid - 192, b = idx >> 3, ks = idx & 7;
      float part = dot4<108>(P.W_ktm + (size_t)ng * KC + ks * 108,
                             kcO + (size_t)(b0 + b) * KC + ks * 108);
      part += __shfl_xor(part, 1);
      part += __shfl_xor(part, 2);
      part += __shfl_xor(part, 4);
      if (ks == 0)
        P.mbon[(b0 + b) * MB + ng] = tanhf(part + P.b_mbon[ng]);
    }
    bar_sync(cnt, gen, lg, tid);

    // ================= Stage B: pn_i (direct L2, low reuse) + y_{t-1} =================
    if (tid < 112) {
      int b = tid & 15, jl = tid >> 4, j = ng * 7 + jl;
      const float* ornRow = ornN + (size_t)(b0 + b) * ORN;
      const float* lnRow  = lnO  + (size_t)(b0 + b) * LN;
      const float* pnRow  = pnO  + (size_t)(b0 + b) * PN;
      float acc = P.b_pn[j]
        + dot4<ORN>(P.W_otp + (size_t)j * ORN, ornRow)
        + dot4<LN> (P.W_ltp + (size_t)j * LN,  lnRow)
        + dot4<PN> (P.W_ptp + (size_t)j * PN,  pnRow);
      pnN[(size_t)(b0 + b) * PN + j] = tanhf(acc);
    } else if (i == 0 && s > 0) {  // y_{t-1}: rank-16 readout from mbon
      for (int o = tid - 112; o < BT * 90; o += 400) {
        int b = o / 90, jl = o - b * 90, j = ng * 90 + jl;
        float acc = P.readout_b[j]
          + dot4<MB>(P.readout_w + (size_t)j * MB, P.mbon + (size_t)(b0 + b) * MB);
        P.y[((size_t)(b0 + b) * Tst + (t - 1)) * HID + j] = acc;
      }
    }
    bar_sync(cnt, gen, lg, tid);

    // ================= Stage C: kc_i (0-431, LDS) + ln_i (448-511, direct L2) =================
    load_seg(act, 996, 0,   kcO,    KC, b0, tid);
    load_seg(act, 996, 864, pnN,    PN, b0, tid);
    load_seg(act, 996, 976, P.mbon, MB, b0, tid);
    __syncthreads();
    if (tid < 432) {
      int b = tid & 15, jp = tid >> 4;
      int j0 = ng * 54 + jp * 2, j1 = j0 + 1;
      float r0 = P.b_kc[j0], r1 = P.b_kc[j1];
      ddot<KC>(P.W_ktk + (size_t)j0 * KC, P.W_ktk + (size_t)j1 * KC, act + b * 996, r0, r1);
      ddot<PN>(P.W_ptk + (size_t)j0 * PN, P.W_ptk + (size_t)j1 * PN, act + b * 996 + 864, r0, r1);
      ddot<MB>(P.W_mtk + (size_t)j0 * MB, P.W_mtk + (size_t)j1 * MB, act + b * 996 + 976, r0, r1);
      kcN[(size_t)(b0 + b) * KC + j0] = tanhf(r0);
      kcN[(size_t)(b0 + b) * KC + j1] = tanhf(r1);
    } else if (tid >= 448) {
      int b = (tid - 448) & 15, jl = (tid - 448) >> 4, j = ng * 4 + jl;
      const float* ornRow = ornN + (size_t)(b0 + b) * ORN;
      const float* pnRow  = pnN  + (size_t)(b0 + b) * PN;
      const float* lnRow  = lnO  + (size_t)(b0 + b) * LN;
      float acc = P.b_ln[j]
        + dot4<ORN>(P.W_otl + (size_t)j * ORN, ornRow)
        + dot4<PN> (P.W_ptl + (size_t)j * PN,  pnRow)
        + dot4<LN> (P.W_ltl + (size_t)j * LN,  lnRow);
      lnN[(size_t)(b0 + b) * LN + j] = tanhf(acc);
    }
    bar_sync(cnt, gen, lg, tid);
  }

  // ================= tail: mbon_{511}, y_{127}, h2 =================
  if (tid >= 192 && tid < 320) {
    int idx = tid - 192, b = idx >> 3, ks = idx & 7;
    float part = dot4<108>(P.W_ktm + (size_t)ng * KC + ks * 108,
                           P.kc1 + (size_t)(b0 + b) * KC + ks * 108);
    part += __shfl_xor(part, 1);
    part += __shfl_xor(part, 2);
    part += __shfl_xor(part, 4);
    if (ks == 0)
      P.mbon[(b0 + b) * MB + ng] = tanhf(part + P.b_mbon[ng]);
  }
  bar_sync(cnt, gen, lg, tid);
  for (int o = tid; o < BT * 90; o += NTHREADS) {
    int b = o / 90, jl = o - b * 90, j = ng * 90 + jl;
    float acc = P.readout_b[j]
      + dot4<MB>(P.readout_w + (size_t)j * MB, P.mbon + (size_t)(b0 + b) * MB);
    P.y[((size_t)(b0 + b) * Tst + (Tst - 1)) * HID + j] = acc;
  }
  for (int idx = tid; idx < BT * 90; idx += NTHREADS) {
    int b = idx / 90, pos = idx - b * 90, gb = b0 + b;
    float v; int hp;
    if      (pos < 24) { v = P.orn1[(size_t)gb * ORN + ng * 24 + pos]; hp = ng * 24 + pos; }
    else if (pos < 31) { int l = pos - 24; v = P.pn1[gb * PN + ng * 7 + l]; hp = 384 + ng * 7 + l; }
    else if (pos < 35) { int l = pos - 31; v = P.ln1[gb * LN + ng * 4 + l]; hp = 496 + ng * 4 + l; }
    else if (pos < 89) { int l = pos - 35; v = P.kc1[(size_t)gb * KC + ng * 54 + l]; hp = 560 + ng * 54 + l; }
    else               { v = P.mbon[gb * MB + ng]; hp = 1424 + ng; }
    P.h2[(size_t)gb * HID + hp] = v;
  }
}

extern "C" void kernel_launch(void* const* d_in, const int* in_sizes, int n_in,
                              void* d_out, int out_size, void* d_ws, size_t ws_size,
                              hipStream_t stream) {
  Params P;
  P.obs       = (const float*)d_in[0];
  P.h         = (const float*)d_in[1];
  P.in_orn_w  = (const float*)d_in[2];
  P.in_orn_b  = (const float*)d_in[3];
  P.W_oto     = (const float*)d_in[4];
  P.W_lto     = (const float*)d_in[5];
  P.W_otp     = (const float*)d_in[6];
  P.W_ltp     = (const float*)d_in[7];
  P.W_ptp     = (const float*)d_in[8];
  P.W_otl     = (const float*)d_in[9];
  P.W_ptl     = (const float*)d_in[10];
  P.W_ltl     = (const float*)d_in[11];
  P.W_ktk     = (const float*)d_in[12];
  P.W_mtk     = (const float*)d_in[13];
  P.W_ptk     = (const float*)d_in[14];
  P.W_ktm     = (const float*)d_in[15];
  P.b_orn     = (const float*)d_in[16];
  P.b_pn      = (const float*)d_in[17];
  P.b_ln      = (const float*)d_in[18];
  P.b_kc      = (const float*)d_in[19];
  P.b_mbon    = (const float*)d_in[20];
  P.readout_w = (const float*)d_in[21];
  P.readout_b = (const float*)d_in[22];

  float* ws = (float*)d_ws;
  size_t off = 0;
  P.orn0 = ws + off; off += (size_t)Bsz * ORN;
  P.orn1 = ws + off; off += (size_t)Bsz * ORN;
  P.pn0  = ws + off; off += (size_t)Bsz * PN;
  P.pn1  = ws + off; off += (size_t)Bsz * PN;
  P.ln0  = ws + off; off += (size_t)Bsz * LN;
  P.ln1  = ws + off; off += (size_t)Bsz * LN;
  P.kc0  = ws + off; off += (size_t)Bsz * KC;
  P.kc1  = ws + off; off += (size_t)Bsz * KC;
  P.mbon = ws + off; off += (size_t)Bsz * MB;
  P.bar  = (int*)(ws + off); off += 16 * 64;  // 16 batch groups x 64 ints (cnt/gen cachelines)

  P.y  = (float*)d_out;
  P.h2 = (float*)d_out + (size_t)Bsz * Tst * HID;

  void* args[] = { &P };
  hipLaunchCooperativeKernel((void*)conn_kernel, dim3(256), dim3(NTHREADS), args, 0, stream);
}